// Round 12
// baseline (448.890 us; speedup 1.0000x reference)
//
#include <hip/hip_runtime.h>
#include <math.h>

#define N_TOTAL 30000
#define NPER 10000
#define NEDGE 500000
#define NREL 6
#define SLOPE 0.2f
#define WCAP 4        // register edge capacity per lane (4*64 = 256 edges/wave)

typedef __attribute__((ext_vector_type(4))) float f32x4;
typedef __attribute__((ext_vector_type(8))) short s16x8;
typedef __attribute__((ext_vector_type(4))) short s16x4;
typedef unsigned short u16;
typedef unsigned int u32;

__device__ __forceinline__ u16 f2bf(float v) {
  u32 x = __float_as_uint(v);
  u32 r = (x + 0x7fffu + ((x >> 16) & 1u)) >> 16;  // RNE
  return (u16)r;
}
__device__ __forceinline__ float bf2f(u16 u) {
  return __uint_as_float(((u32)u) << 16);
}

// ---------------------------------------------------------------------------
// Split-precision bf16 MFMA GEMM core (r6-proven config), depth-1 prefetch:
//   prologue: LOAD(t0) -> regs
//   loop: {WRITE(regs->LDS); barrier; LOAD(t+1); ds_read+MFMA; barrier}
// A staged f32 -> hi/lo bf16 (2 MFMAs/frag): only weight rounding remains.
// Tile BM=64, BN=128, BK=64. 256 thr = 4 waves (2x2), wave tile 32x64.
// LDS 32KB: As 8K + Aslo 8K + Bs 16K -> 5 blocks/CU.
// XOR-swizzle byte ^= (row&7)<<4 (measured 0 conflicts).
// C/D frag: col=lane&15, row=(lane>>4)*4+reg [m89/m91 verified].
// ---------------------------------------------------------------------------
template<bool BIAS, bool ELU, bool ADD, bool RAW>
__device__ __forceinline__ void gemm_core(
    const float* __restrict__ A, const u16* __restrict__ Bt,
    const float* __restrict__ bias, const float* __restrict__ add,
    float* __restrict__ C, int M, int K, int Kp, int kbeg, int kend)
{
  __shared__ char As[64 * 128];
  __shared__ char Aslo[64 * 128];
  __shared__ char Bs[128 * 128];
  const int tid = threadIdx.x;
  const int bm = blockIdx.x * 64;
  const int lane = tid & 63;
  const int wave = tid >> 6;
  const int wr = wave >> 1, wc = wave & 1;
  const int lane16 = lane & 15, lhalf = lane >> 4;

  const int a_row0 = tid >> 4;            // + it*16 (it<4 -> rows 0..63)
  const int a_kc = (tid & 15) << 2;
  const int b_row0 = tid >> 3;            // + it*32 (it<4 -> rows 0..127)
  const int b_kc = (tid & 7) << 3;

  float4 pa[4];
  s16x8 pb[4];

  auto LOAD = [&](int k0) {
    #pragma unroll
    for (int it = 0; it < 4; it++) {
      int gr = bm + a_row0 + it * 16, gk = k0 + a_kc;
      float4 v = make_float4(0.f, 0.f, 0.f, 0.f);
      if (gr < M && gk < K) v = *(const float4*)&A[(size_t)gr * K + gk];
      pa[it] = v;
    }
    #pragma unroll
    for (int it = 0; it < 4; it++) {
      int row = b_row0 + it * 32;
      pb[it] = *(const s16x8*)&Bt[(size_t)row * Kp + k0 + b_kc];
    }
  };

  auto WRITE = [&]() {
    #pragma unroll
    for (int it = 0; it < 4; it++) {
      int row = a_row0 + it * 16;
      float vv[4] = {pa[it].x, pa[it].y, pa[it].z, pa[it].w};
      s16x4 hi, lo;
      #pragma unroll
      for (int j = 0; j < 4; j++) {
        u16 h = f2bf(vv[j]);
        hi[j] = (short)h;
        lo[j] = (short)f2bf(vv[j] - bf2f(h));
      }
      int boff = row * 128 + ((a_kc * 2) ^ ((row & 7) << 4));
      *(s16x4*)(As + boff) = hi;
      *(s16x4*)(Aslo + boff) = lo;
    }
    #pragma unroll
    for (int it = 0; it < 4; it++) {
      int row = b_row0 + it * 32;
      *(s16x8*)(Bs + row * 128 + ((b_kc * 2) ^ ((row & 7) << 4))) = pb[it];
    }
  };

  f32x4 acc[2][4];
  #pragma unroll
  for (int mi = 0; mi < 2; mi++)
    #pragma unroll
    for (int ni = 0; ni < 4; ni++)
      #pragma unroll
      for (int q = 0; q < 4; q++) acc[mi][ni][q] = 0.f;

  auto MFMA_STEP = [&]() {
    #pragma unroll
    for (int kk = 0; kk < 2; kk++) {
      const int kbyte = kk * 64 + lhalf * 16;
      s16x8 afh[2], afl[2], bfr[4];
      #pragma unroll
      for (int mi = 0; mi < 2; mi++) {
        int row = wr * 32 + mi * 16 + lane16;
        int boff = row * 128 + (kbyte ^ ((row & 7) << 4));
        afh[mi] = *(const s16x8*)(As + boff);
        afl[mi] = *(const s16x8*)(Aslo + boff);
      }
      #pragma unroll
      for (int ni = 0; ni < 4; ni++) {
        int row = wc * 64 + ni * 16 + lane16;
        bfr[ni] = *(const s16x8*)(Bs + row * 128 + (kbyte ^ ((row & 7) << 4)));
      }
      #pragma unroll
      for (int mi = 0; mi < 2; mi++)
        #pragma unroll
        for (int ni = 0; ni < 4; ni++) {
          acc[mi][ni] = __builtin_amdgcn_mfma_f32_16x16x32_bf16(
              afl[mi], bfr[ni], acc[mi][ni], 0, 0, 0);
          acc[mi][ni] = __builtin_amdgcn_mfma_f32_16x16x32_bf16(
              afh[mi], bfr[ni], acc[mi][ni], 0, 0, 0);
        }
    }
  };

  const int nt = (kend - kbeg) >> 6;
  LOAD(kbeg);
  for (int t = 0; t < nt; t++) {
    WRITE();
    __syncthreads();
    if (t + 1 < nt) LOAD(kbeg + (t + 1) * 64);
    MFMA_STEP();
    __syncthreads();
  }

  float bcol[4];
  #pragma unroll
  for (int ni = 0; ni < 4; ni++) {
    int col = wc * 64 + ni * 16 + lane16;
    if (BIAS) bcol[ni] = bias[col];
  }
  #pragma unroll
  for (int mi = 0; mi < 2; mi++) {
    #pragma unroll
    for (int q = 0; q < 4; q++) {
      int grow = bm + wr * 32 + mi * 16 + lhalf * 4 + q;
      if (grow < M) {
        #pragma unroll
        for (int ni = 0; ni < 4; ni++) {
          float v = acc[mi][ni][q];
          int col = wc * 64 + ni * 16 + lane16;
          if (BIAS) v += bcol[ni];
          if (ADD) v += add[(size_t)grow * 128 + col];
          if (!RAW && ELU) v = v > 0.f ? v : expm1f(v);
          C[(size_t)grow * 128 + col] = v;
        }
      }
    }
  }
}

struct GB {
  const float* A[3];
  const u16* Bt[3];
  const float* bias[3];
  const float* add[3];
  float* C[3];
  int K[3];
  int Kp[3];
};

template<bool BIAS, bool ELU, bool ADD>
__global__ __launch_bounds__(256, 2)
void gemm_mfma(GB gb, int M)
{
  int z = blockIdx.z;
  gemm_core<BIAS, ELU, ADD, false>(gb.A[z], gb.Bt[z], gb.bias[z], gb.add[z],
                                   gb.C[z], M, gb.K[z], gb.Kp[z], 0, gb.Kp[z]);
}

struct SK {
  const float* A[3];
  const u16* Bt[3];
  float* C[3];          // partial base per z: + chunk_idx*M*128
  int K[3];
  int Kp[3];
};

__global__ __launch_bounds__(256, 2)
void gemm_splitk(SK sk, int M, int chunk)
{
  int z = blockIdx.z;
  int cb = blockIdx.y * chunk;
  if (cb >= sk.Kp[z]) return;
  int kend = (cb + chunk < sk.Kp[z]) ? cb + chunk : sk.Kp[z];
  float* C = sk.C[z] + (size_t)blockIdx.y * M * 128;
  gemm_core<false, false, false, true>(sk.A[z], sk.Bt[z], nullptr, nullptr,
                                       C, M, sk.K[z], sk.Kp[z], cb, kend);
}

struct RP { const float* bias[3]; int nch[3]; };

__global__ __launch_bounds__(256)
void reduce_proj(const float* __restrict__ part, RP rp, float* __restrict__ Xf)
{
  int z = blockIdx.z;
  int i = blockIdx.x * 256 + threadIdx.x;   // over NPER*128
  int c = i & 127;
  int nch = rp.nch[z];
  const float* base = part + (size_t)z * 4 * NPER * 128 + i;
  float s = 0.f;
  for (int ch = 0; ch < nch; ch++) s += base[(size_t)ch * NPER * 128];
  s += rp.bias[z][c];
  Xf[(size_t)z * NPER * 128 + i] = s > 0.f ? s : expm1f(s);
}

// transform reduce: Hf = elu(part0 + part1 + bias + SL)
__global__ __launch_bounds__(256)
void reduce_tr(const float* __restrict__ part, const float* __restrict__ bias,
               const float* __restrict__ sl, float* __restrict__ h)
{
  int i = blockIdx.x * 256 + threadIdx.x;   // over N_TOTAL*128
  float v = part[i] + part[(size_t)N_TOTAL * 128 + i] + bias[i & 127] + sl[i];
  h[i] = v > 0.f ? v : expm1f(v);
}

// ---------------------------------------------------------------------------
// Weight convert: src f32 [K][128] -> dst bf16 [128][Kp] (transposed, padded)
// ---------------------------------------------------------------------------
struct CW {
  const float* src[9];
  u16* dst[9];
  int K[9];
  int Kp[9];
};

__global__ __launch_bounds__(256)
void conv_w(CW cw) {
  int z = blockIdx.z;
  int K = cw.K[z], Kp = cw.Kp[z];
  int idx = blockIdx.x * 256 + threadIdx.x;
  if (idx >= 128 * Kp) return;
  int kq = idx >> 7, n = idx & 127;
  cw.dst[z][(size_t)n * Kp + kq] =
      (kq < K) ? f2bf(cw.src[z][(size_t)kq * 128 + n]) : (u16)0;
}

// ---------------------------------------------------------------------------
// Attention-score precompute (exact f32): Wq[r]=W[r]@q; QD[r,n]=X[n,:].Wq[r]
// ---------------------------------------------------------------------------
__global__ __launch_bounds__(128)
void wqk_kernel(const float* __restrict__ W, const float* __restrict__ q,
                const float* __restrict__ k, float* __restrict__ wq,
                float* __restrict__ wk)
{
  int r = blockIdx.x;
  int t = threadIdx.x;
  const float* Wr = W + (size_t)r * 128 * 128 + (size_t)t * 128;
  float aq = 0.f, ak = 0.f;
  for (int o = 0; o < 128; o++) {
    float w = Wr[o];
    aq = fmaf(w, q[o], aq);
    ak = fmaf(w, k[o], ak);
  }
  wq[r * 128 + t] = aq;
  wk[r * 128 + t] = ak;
}

__global__ __launch_bounds__(256)
void qdkd_kernel(const float* __restrict__ Xf, const float* __restrict__ wq,
                 const float* __restrict__ wk, float* __restrict__ QD,
                 float* __restrict__ KD)
{
  __shared__ float sq[NREL * 128], sk[NREL * 128];
  for (int i = threadIdx.x; i < NREL * 128; i += 256) { sq[i] = wq[i]; sk[i] = wk[i]; }
  __syncthreads();
  int n = blockIdx.x * 256 + threadIdx.x;
  if (n >= N_TOTAL) return;
  float aq[NREL], ak[NREL];
  #pragma unroll
  for (int r = 0; r < NREL; r++) { aq[r] = 0.f; ak[r] = 0.f; }
  for (int kc = 0; kc < 128; kc += 4) {
    float4 x = *(const float4*)&Xf[(size_t)n * 128 + kc];
    #pragma unroll
    for (int r = 0; r < NREL; r++) {
      aq[r] += x.x * sq[r * 128 + kc] + x.y * sq[r * 128 + kc + 1]
             + x.z * sq[r * 128 + kc + 2] + x.w * sq[r * 128 + kc + 3];
      ak[r] += x.x * sk[r * 128 + kc] + x.y * sk[r * 128 + kc + 1]
             + x.z * sk[r * 128 + kc + 2] + x.w * sk[r * 128 + kc + 3];
    }
  }
  #pragma unroll
  for (int r = 0; r < NREL; r++) {
    QD[(size_t)r * N_TOTAL + n] = aq[r];
    KD[(size_t)r * N_TOTAL + n] = ak[r];
  }
}

// ---------------------------------------------------------------------------
// CSR build; edge_fill writes CSR-ordered packed meta: src | (t<<15)
// ---------------------------------------------------------------------------
__global__ __launch_bounds__(256)
void edge_count(const int* __restrict__ dst, int* __restrict__ cnt) {
  int e = blockIdx.x * 256 + threadIdx.x;
  if (e < NEDGE) atomicAdd(&cnt[dst[e]], 1);
}

__global__ __launch_bounds__(1024)
void scan_kernel(const int* __restrict__ cnt, int* __restrict__ off,
                 int* __restrict__ cur) {
  __shared__ int ps[1024];
  const int t = threadIdx.x;
  const int CH = (N_TOTAL + 1023) / 1024;
  const int base = t * CH;
  int s = 0;
  for (int i = 0; i < CH; i++) {
    int idx = base + i;
    if (idx < N_TOTAL) s += cnt[idx];
  }
  ps[t] = s;
  __syncthreads();
  for (int o = 1; o < 1024; o <<= 1) {
    int v = (t >= o) ? ps[t - o] : 0;
    __syncthreads();
    ps[t] += v;
    __syncthreads();
  }
  int run = ps[t] - s;
  for (int i = 0; i < CH; i++) {
    int idx = base + i;
    if (idx < N_TOTAL) {
      off[idx] = run; cur[idx] = run;
      run += cnt[idx];
    }
  }
  if (t == 1023) off[N_TOTAL] = run;
}

__global__ __launch_bounds__(256)
void edge_fill(const int* __restrict__ dst, const int* __restrict__ src,
               const int* __restrict__ et, int* __restrict__ cur,
               int* __restrict__ meta) {
  int e = blockIdx.x * 256 + threadIdx.x;
  if (e >= NEDGE) return;
  int p = atomicAdd(&cur[dst[e]], 1);
  meta[p] = src[e] | (et[e] << 15);
}

// ---------------------------------------------------------------------------
// Wave-per-destination attention + per-relation aggregation. No LDS, no
// barriers. agg[d][r][128] output.
// ---------------------------------------------------------------------------
__global__ __launch_bounds__(256)
void csr_aggw(const int* __restrict__ off, const int* __restrict__ meta,
              const float* __restrict__ qd, const float* __restrict__ kd,
              const float* __restrict__ xrow, float* __restrict__ agg)
{
  const int d = blockIdx.x * 4 + (threadIdx.x >> 6);
  const int lane = threadIdx.x & 63;
  if (d >= N_TOTAL) return;
  const int n0 = off[d];
  const int deg = off[d + 1] - n0;

  float2 accr[NREL];
  #pragma unroll
  for (int r = 0; r < NREL; r++) accr[r] = make_float2(0.f, 0.f);

  float qrow[NREL];
  #pragma unroll
  for (int r = 0; r < NREL; r++) qrow[r] = qd[r * N_TOTAL + d];

  if (deg > 0) {
    if (deg <= 64 * WCAP) {
      int mreg[WCAP];
      float areg[WCAP];
      const int nc = (deg + 63) >> 6;
      float lmax = -3.0e38f;
      #pragma unroll
      for (int c = 0; c < WCAP; c++) {
        mreg[c] = 0; areg[c] = -3.0e38f;
        int i = c * 64 + lane;
        if (c < nc && i < deg) {
          int mm = meta[n0 + i];
          int s_ = mm & 0x7FFF, t = mm >> 15;
          float a = qrow[t] + kd[t * N_TOTAL + s_];
          a = (a > 0.f) ? a : SLOPE * a;
          mreg[c] = mm; areg[c] = a;
          lmax = fmaxf(lmax, a);
        }
      }
      #pragma unroll
      for (int m = 32; m; m >>= 1) lmax = fmaxf(lmax, __shfl_xor(lmax, m));
      float lsum = 0.f;
      #pragma unroll
      for (int c = 0; c < WCAP; c++) {
        int i = c * 64 + lane;
        if (c < nc && i < deg) {
          areg[c] = expf(areg[c] - lmax);
          lsum += areg[c];
        }
      }
      #pragma unroll
      for (int m = 32; m; m >>= 1) lsum += __shfl_xor(lsum, m);
      const float scale = (float)deg / lsum;
      for (int i = 0; i < deg; i++) {
        int c = i >> 6, l = i & 63;
        float cf = 0.f; int mm = 0;
        #pragma unroll
        for (int cc = 0; cc < WCAP; cc++) {
          if (cc == c) { cf = __shfl(areg[cc], l); mm = __shfl(mreg[cc], l); }
        }
        cf *= scale;
        int s_ = mm & 0x7FFF, t = mm >> 15;
        float2 v = *(const float2*)&xrow[(size_t)s_ * 128 + lane * 2];
        float2 cv = make_float2(cf * v.x, cf * v.y);
        #pragma unroll
        for (int r = 0; r < NREL; r++) {
          bool hit = (t == r);
          accr[r].x += hit ? cv.x : 0.f;
          accr[r].y += hit ? cv.y : 0.f;
        }
      }
    } else {
      float m = -3.0e38f;
      for (int i = 0; i < deg; i++) {
        int mm = meta[n0 + i];
        int s_ = mm & 0x7FFF, t = mm >> 15;
        float a = qrow[t] + kd[t * N_TOTAL + s_];
        a = (a > 0.f) ? a : SLOPE * a;
        m = fmaxf(m, a);
      }
      float ssum = 0.f;
      for (int i = 0; i < deg; i++) {
        int mm = meta[n0 + i];
        int s_ = mm & 0x7FFF, t = mm >> 15;
        float a = qrow[t] + kd[t * N_TOTAL + s_];
        a = (a > 0.f) ? a : SLOPE * a;
        ssum += expf(a - m);
      }
      const float scale = (float)deg / ssum;
      for (int i = 0; i < deg; i++) {
        int mm = meta[n0 + i];
        int s_ = mm & 0x7FFF, t = mm >> 15;
        float a = qrow[t] + kd[t * N_TOTAL + s_];
        a = (a > 0.f) ? a : SLOPE * a;
        float cf = expf(a - m) * scale;
        float2 v = *(const float2*)&xrow[(size_t)s_ * 128 + lane * 2];
        float2 cv = make_float2(cf * v.x, cf * v.y);
        #pragma unroll
        for (int r = 0; r < NREL; r++) {
          bool hit = (t == r);
          accr[r].x += hit ? cv.x : 0.f;
          accr[r].y += hit ? cv.y : 0.f;
        }
      }
    }
  }
  #pragma unroll
  for (int r = 0; r < NREL; r++)
    *(float2*)&agg[((size_t)d * NREL + r) * 128 + lane * 2] = accr[r];
}

__global__ __launch_bounds__(256)
void lin2_kernel(const float* __restrict__ z, const float* __restrict__ W,
                 const float* __restrict__ b, float* __restrict__ out)
{
  int row = blockIdx.x * 4 + (threadIdx.x >> 6);
  int lane = threadIdx.x & 63;
  if (row >= NPER) return;
  float p[5] = {0.f, 0.f, 0.f, 0.f, 0.f};
  #pragma unroll
  for (int h = 0; h < 2; h++) {
    int kidx = lane + h * 64;
    float zv = z[(size_t)row * 128 + kidx];
    #pragma unroll
    for (int j = 0; j < 5; j++) p[j] = fmaf(zv, W[kidx * 5 + j], p[j]);
  }
  #pragma unroll
  for (int mm = 32; mm; mm >>= 1)
    #pragma unroll
    for (int j = 0; j < 5; j++) p[j] += __shfl_xor(p[j], mm);
  if (lane == 0) {
    #pragma unroll
    for (int j = 0; j < 5; j++) out[(size_t)row * 5 + j] = p[j] + b[j];
  }
}

// ---------------------------------------------------------------------------
extern "C" void kernel_launch(void* const* d_in, const int* in_sizes, int n_in,
                              void* d_out, int out_size, void* d_ws, size_t ws_size,
                              hipStream_t stream) {
  const float* xs[3] = {(const float*)d_in[0], (const float*)d_in[1], (const float*)d_in[2]};
  const float* projW[3] = {(const float*)d_in[3], (const float*)d_in[5], (const float*)d_in[7]};
  const float* projb[3] = {(const float*)d_in[4], (const float*)d_in[6], (const float*)d_in[8]};
  const float* slW[3]   = {(const float*)d_in[9], (const float*)d_in[11], (const float*)d_in[13]};
  const float* slb[3]   = {(const float*)d_in[10], (const float*)d_in[12], (const float*)d_in[14]};
  const float* W1 = (const float*)d_in[15];
  const float* q1 = (const float*)d_in[16];
  const float* k1 = (const float*)d_in[17];
  const float* b1 = (const float*)d_in[18];
  const float* W2 = (const float*)d_in[19];
  const float* q2 = (const float*)d_in[20];
  const float* k2 = (const float*)d_in[21];
  const float* b2 = (const float*)d_in[22];
  const float* lin1W = (const float*)d_in[23];
  const float* lin1b = (const float*)d_in[24];
  const float* lin2W = (const float*)d_in[25];
  const float* lin2b = (const float*)d_in[26];
  const int* esrc = (const int*)d_in[27];
  const int* edst = (const int*)d_in[28];
  const int* etyp = (const int*)d_in[29];

  char* wp = (char*)d_ws;
  auto alloc = [&](size_t bytes) -> char* {
    char* p = wp; wp += (bytes + 255) & ~(size_t)255; return p;
  };
  float* Xf  = (float*)alloc((size_t)N_TOTAL * 128 * 4);
  float* SL  = (float*)alloc((size_t)N_TOTAL * 128 * 4);
  float* Hf  = (float*)alloc((size_t)N_TOTAL * 128 * 4);
  float* QD  = (float*)alloc((size_t)NREL * N_TOTAL * 4);
  float* KD  = (float*)alloc((size_t)NREL * N_TOTAL * 4);
  float* Z   = (float*)alloc((size_t)NPER * 128 * 4);
  float* WQ1 = (float*)alloc((size_t)NREL * 128 * 4);
  float* WK1 = (float*)alloc((size_t)NREL * 128 * 4);
  float* WQ2 = (float*)alloc((size_t)NREL * 128 * 4);
  float* WK2 = (float*)alloc((size_t)NREL * 128 * 4);
  int*   CNT = (int*)  alloc((size_t)N_TOTAL * 4);
  int*   OFF = (int*)  alloc((size_t)(N_TOTAL + 1) * 4);
  int*   CUR = (int*)  alloc((size_t)N_TOTAL * 4);
  int*   META= (int*)  alloc((size_t)NEDGE * 4);

  // PART region (61.4 MB): proj partials [3][4][NPER][128]; reused as
  // transform partials [2][N_TOTAL][128] (30.7 MB) inside the layer loop.
  float* PART = (float*)alloc((size_t)3 * 4 * NPER * 128 * 4);
  // AGG [30000][768] f32 (92 MB)
  float* AGG  = (float*)alloc((size_t)N_TOTAL * NREL * 128 * 4);

  CW cw;
  int nW = 0;
  auto addW = [&](const float* src, int K) {
    int Kp = (K + 63) & ~63;
    cw.src[nW] = src; cw.K[nW] = K; cw.Kp[nW] = Kp;
    cw.dst[nW] = (u16*)alloc((size_t)128 * Kp * 2);
    nW++;
  };
  addW(projW[0], 2000); addW(projW[1], 1500); addW(projW[2], 1000);  // 0-2
  addW(slW[0], 128); addW(slW[1], 128); addW(slW[2], 128);           // 3-5
  addW(W1, NREL * 128);   // 6: stacked [768][128] -> Bt [128][768]
  addW(W2, NREL * 128);   // 7
  addW(lin1W, 128);       // 8

  const int gridM_per = (NPER + 63) / 64;     // 157
  const int gridM_tot = (N_TOTAL + 63) / 64;  // 469
  const int gridE = (NEDGE + 255) / 256;

  // ---- CSR build ----
  hipMemsetAsync(CNT, 0, (size_t)N_TOTAL * 4, stream);
  edge_count<<<gridE, 256, 0, stream>>>(edst, CNT);
  scan_kernel<<<1, 1024, 0, stream>>>(CNT, OFF, CUR);
  edge_fill<<<gridE, 256, 0, stream>>>(edst, esrc, etyp, CUR, META);

  conv_w<<<dim3(1024, 1, 9), 256, 0, stream>>>(cw);
  wqk_kernel<<<NREL, 128, 0, stream>>>(W1, q1, k1, WQ1, WK1);
  wqk_kernel<<<NREL, 128, 0, stream>>>(W2, q2, k2, WQ2, WK2);

  // ---- projections via split-K (chunks of 512 — r6-proven) ----
  {
    SK sk;
    for (int z = 0; z < 3; z++) {
      sk.A[z] = xs[z]; sk.Bt[z] = cw.dst[z];
      sk.C[z] = PART + (size_t)z * 4 * NPER * 128;
      sk.K[z] = cw.K[z]; sk.Kp[z] = cw.Kp[z];
    }
    gemm_splitk<<<dim3(gridM_per, 4, 3), 256, 0, stream>>>(sk, NPER, 512);
    RP rp;
    for (int z = 0; z < 3; z++) { rp.bias[z] = projb[z]; rp.nch[z] = cw.Kp[z] / 512; }
    reduce_proj<<<dim3(NPER * 128 / 256, 1, 3), 256, 0, stream>>>(PART, rp, Xf);
  }
  // ---- self-loops: SL = Xf_i @ slW_i + slb_i ----
  {
    GB g;
    for (int z = 0; z < 3; z++) {
      g.A[z] = Xf + (size_t)z * NPER * 128; g.Bt[z] = cw.dst[3 + z];
      g.bias[z] = slb[z]; g.add[z] = nullptr;
      g.C[z] = SL + (size_t)z * NPER * 128;
      g.K[z] = 128; g.Kp[z] = 128;
    }
    gemm_mfma<true, false, false><<<dim3(gridM_per, 1, 3), 256, 0, stream>>>(g, NPER);
  }

  for (int layer = 0; layer < 2; layer++) {
    const float* Ain = (layer == 0) ? Xf : Hf;
    const float* WQ = (layer == 0) ? WQ1 : WQ2;
    const float* WK = (layer == 0) ? WK1 : WK2;
    const float* bb = (layer == 0) ? b1 : b2;
    const u16* Wstk = cw.dst[6 + layer];

    qdkd_kernel<<<(N_TOTAL + 255) / 256, 256, 0, stream>>>(Ain, WQ, WK, QD, KD);
    csr_aggw<<<(N_TOTAL + 3) / 4, 256, 0, stream>>>(OFF, META, QD, KD, Ain, AGG);
    // transform: Hf = elu(AGG[30000,768] @ Wstack[768,128] + b + SL)
    // ISOLATED EXPERIMENT: split-K x2 (chunk 384) -> 938 blocks (one
    // generation) vs 469 (1.8/CU, TLP-starved). PART reused for partials.
    SK sk;
    sk.A[0] = AGG; sk.Bt[0] = Wstk; sk.C[0] = PART;
    sk.K[0] = NREL * 128; sk.Kp[0] = NREL * 128;
    gemm_splitk<<<dim3(gridM_tot, 2, 1), 256, 0, stream>>>(sk, N_TOTAL, 384);
    reduce_tr<<<(N_TOTAL * 128) / 256, 256, 0, stream>>>(PART, bb, SL, Hf);
  }

  // ---- head ----
  {
    GB g;
    g.A[0] = Hf; g.Bt[0] = cw.dst[8]; g.bias[0] = lin1b; g.add[0] = nullptr; g.C[0] = Z;
    g.K[0] = 128; g.Kp[0] = 128;
    gemm_mfma<true, true, false><<<dim3(gridM_per, 1, 1), 256, 0, stream>>>(g, NPER);
  }
  lin2_kernel<<<(NPER + 3) / 4, 256, 0, stream>>>(Z, lin2W, lin2b, (float*)d_out);
}

// Round 13
// 442.887 us; speedup vs baseline: 1.0136x; 1.0136x over previous
//
#include <hip/hip_runtime.h>
#include <math.h>

#define N_TOTAL 30000
#define NPER 10000
#define NEDGE 500000
#define NREL 6
#define SLOPE 0.2f
#define WCAP 4        // register edge capacity per lane (4*64 = 256 edges/wave)

typedef __attribute__((ext_vector_type(4))) float f32x4;
typedef __attribute__((ext_vector_type(8))) short s16x8;
typedef __attribute__((ext_vector_type(4))) short s16x4;
typedef unsigned short u16;
typedef unsigned int u32;

__device__ __forceinline__ u16 f2bf(float v) {
  u32 x = __float_as_uint(v);
  u32 r = (x + 0x7fffu + ((x >> 16) & 1u)) >> 16;  // RNE
  return (u16)r;
}
__device__ __forceinline__ float bf2f(u16 u) {
  return __uint_as_float(((u32)u) << 16);
}

// ---------------------------------------------------------------------------
// Split-precision bf16 MFMA GEMM core (r6-proven config), depth-1 prefetch:
//   prologue: LOAD(t0) -> regs
//   loop: {WRITE(regs->LDS); barrier; LOAD(t+1); ds_read+MFMA; barrier}
// A staged f32 -> hi/lo bf16 (2 MFMAs/frag): only weight rounding remains.
// Tile BM=64, BN=128, BK=64. 256 thr = 4 waves (2x2), wave tile 32x64.
// LDS 32KB: As 8K + Aslo 8K + Bs 16K -> 5 blocks/CU.
// XOR-swizzle byte ^= (row&7)<<4 (measured 0 conflicts).
// C/D frag: col=lane&15, row=(lane>>4)*4+reg [m89/m91 verified].
// ---------------------------------------------------------------------------
template<bool BIAS, bool ELU, bool ADD, bool RAW>
__device__ __forceinline__ void gemm_core(
    const float* __restrict__ A, const u16* __restrict__ Bt,
    const float* __restrict__ bias, const float* __restrict__ add,
    float* __restrict__ C, int M, int K, int Kp, int kbeg, int kend)
{
  __shared__ char As[64 * 128];
  __shared__ char Aslo[64 * 128];
  __shared__ char Bs[128 * 128];
  const int tid = threadIdx.x;
  const int bm = blockIdx.x * 64;
  const int lane = tid & 63;
  const int wave = tid >> 6;
  const int wr = wave >> 1, wc = wave & 1;
  const int lane16 = lane & 15, lhalf = lane >> 4;

  const int a_row0 = tid >> 4;            // + it*16 (it<4 -> rows 0..63)
  const int a_kc = (tid & 15) << 2;
  const int b_row0 = tid >> 3;            // + it*32 (it<4 -> rows 0..127)
  const int b_kc = (tid & 7) << 3;

  float4 pa[4];
  s16x8 pb[4];

  auto LOAD = [&](int k0) {
    #pragma unroll
    for (int it = 0; it < 4; it++) {
      int gr = bm + a_row0 + it * 16, gk = k0 + a_kc;
      float4 v = make_float4(0.f, 0.f, 0.f, 0.f);
      if (gr < M && gk < K) v = *(const float4*)&A[(size_t)gr * K + gk];
      pa[it] = v;
    }
    #pragma unroll
    for (int it = 0; it < 4; it++) {
      int row = b_row0 + it * 32;
      pb[it] = *(const s16x8*)&Bt[(size_t)row * Kp + k0 + b_kc];
    }
  };

  auto WRITE = [&]() {
    #pragma unroll
    for (int it = 0; it < 4; it++) {
      int row = a_row0 + it * 16;
      float vv[4] = {pa[it].x, pa[it].y, pa[it].z, pa[it].w};
      s16x4 hi, lo;
      #pragma unroll
      for (int j = 0; j < 4; j++) {
        u16 h = f2bf(vv[j]);
        hi[j] = (short)h;
        lo[j] = (short)f2bf(vv[j] - bf2f(h));
      }
      int boff = row * 128 + ((a_kc * 2) ^ ((row & 7) << 4));
      *(s16x4*)(As + boff) = hi;
      *(s16x4*)(Aslo + boff) = lo;
    }
    #pragma unroll
    for (int it = 0; it < 4; it++) {
      int row = b_row0 + it * 32;
      *(s16x8*)(Bs + row * 128 + ((b_kc * 2) ^ ((row & 7) << 4))) = pb[it];
    }
  };

  f32x4 acc[2][4];
  #pragma unroll
  for (int mi = 0; mi < 2; mi++)
    #pragma unroll
    for (int ni = 0; ni < 4; ni++)
      #pragma unroll
      for (int q = 0; q < 4; q++) acc[mi][ni][q] = 0.f;

  auto MFMA_STEP = [&]() {
    #pragma unroll
    for (int kk = 0; kk < 2; kk++) {
      const int kbyte = kk * 64 + lhalf * 16;
      s16x8 afh[2], afl[2], bfr[4];
      #pragma unroll
      for (int mi = 0; mi < 2; mi++) {
        int row = wr * 32 + mi * 16 + lane16;
        int boff = row * 128 + (kbyte ^ ((row & 7) << 4));
        afh[mi] = *(const s16x8*)(As + boff);
        afl[mi] = *(const s16x8*)(Aslo + boff);
      }
      #pragma unroll
      for (int ni = 0; ni < 4; ni++) {
        int row = wc * 64 + ni * 16 + lane16;
        bfr[ni] = *(const s16x8*)(Bs + row * 128 + (kbyte ^ ((row & 7) << 4)));
      }
      #pragma unroll
      for (int mi = 0; mi < 2; mi++)
        #pragma unroll
        for (int ni = 0; ni < 4; ni++) {
          acc[mi][ni] = __builtin_amdgcn_mfma_f32_16x16x32_bf16(
              afl[mi], bfr[ni], acc[mi][ni], 0, 0, 0);
          acc[mi][ni] = __builtin_amdgcn_mfma_f32_16x16x32_bf16(
              afh[mi], bfr[ni], acc[mi][ni], 0, 0, 0);
        }
    }
  };

  const int nt = (kend - kbeg) >> 6;
  LOAD(kbeg);
  for (int t = 0; t < nt; t++) {
    WRITE();
    __syncthreads();
    if (t + 1 < nt) LOAD(kbeg + (t + 1) * 64);
    MFMA_STEP();
    __syncthreads();
  }

  float bcol[4];
  #pragma unroll
  for (int ni = 0; ni < 4; ni++) {
    int col = wc * 64 + ni * 16 + lane16;
    if (BIAS) bcol[ni] = bias[col];
  }
  #pragma unroll
  for (int mi = 0; mi < 2; mi++) {
    #pragma unroll
    for (int q = 0; q < 4; q++) {
      int grow = bm + wr * 32 + mi * 16 + lhalf * 4 + q;
      if (grow < M) {
        #pragma unroll
        for (int ni = 0; ni < 4; ni++) {
          float v = acc[mi][ni][q];
          int col = wc * 64 + ni * 16 + lane16;
          if (BIAS) v += bcol[ni];
          if (ADD) v += add[(size_t)grow * 128 + col];
          if (!RAW && ELU) v = v > 0.f ? v : expm1f(v);
          C[(size_t)grow * 128 + col] = v;
        }
      }
    }
  }
}

struct GB {
  const float* A[3];
  const u16* Bt[3];
  const float* bias[3];
  const float* add[3];
  float* C[3];
  int K[3];
  int Kp[3];
};

template<bool BIAS, bool ELU, bool ADD>
__global__ __launch_bounds__(256, 2)
void gemm_mfma(GB gb, int M)
{
  int z = blockIdx.z;
  gemm_core<BIAS, ELU, ADD, false>(gb.A[z], gb.Bt[z], gb.bias[z], gb.add[z],
                                   gb.C[z], M, gb.K[z], gb.Kp[z], 0, gb.Kp[z]);
}

struct SK {
  const float* A[3];
  const u16* Bt[3];
  float* C[3];          // partial base per z: + chunk_idx*M*128
  int K[3];
  int Kp[3];
};

__global__ __launch_bounds__(256, 2)
void gemm_splitk(SK sk, int M, int chunk)
{
  int z = blockIdx.z;
  int cb = blockIdx.y * chunk;
  if (cb >= sk.Kp[z]) return;
  int kend = (cb + chunk < sk.Kp[z]) ? cb + chunk : sk.Kp[z];
  float* C = sk.C[z] + (size_t)blockIdx.y * M * 128;
  gemm_core<false, false, false, true>(sk.A[z], sk.Bt[z], nullptr, nullptr,
                                       C, M, sk.K[z], sk.Kp[z], cb, kend);
}

struct RP { const float* bias[3]; int nch[3]; };

__global__ __launch_bounds__(256)
void reduce_proj(const float* __restrict__ part, RP rp, float* __restrict__ Xf)
{
  int z = blockIdx.z;
  int i = blockIdx.x * 256 + threadIdx.x;   // over NPER*128
  int c = i & 127;
  int nch = rp.nch[z];
  const float* base = part + (size_t)z * 4 * NPER * 128 + i;
  float s = 0.f;
  for (int ch = 0; ch < nch; ch++) s += base[(size_t)ch * NPER * 128];
  s += rp.bias[z][c];
  Xf[(size_t)z * NPER * 128 + i] = s > 0.f ? s : expm1f(s);
}

// ---------------------------------------------------------------------------
// Weight convert: src f32 [K][128] -> dst bf16 [128][Kp] (transposed, padded)
// ---------------------------------------------------------------------------
struct CW {
  const float* src[9];
  u16* dst[9];
  int K[9];
  int Kp[9];
};

__global__ __launch_bounds__(256)
void conv_w(CW cw) {
  int z = blockIdx.z;
  int K = cw.K[z], Kp = cw.Kp[z];
  int idx = blockIdx.x * 256 + threadIdx.x;
  if (idx >= 128 * Kp) return;
  int kq = idx >> 7, n = idx & 127;
  cw.dst[z][(size_t)n * Kp + kq] =
      (kq < K) ? f2bf(cw.src[z][(size_t)kq * 128 + n]) : (u16)0;
}

// ---------------------------------------------------------------------------
// Attention-score precompute (exact f32): Wq[r]=W[r]@q; QD[r,n]=X[n,:].Wq[r]
// ---------------------------------------------------------------------------
__global__ __launch_bounds__(128)
void wqk_kernel(const float* __restrict__ W, const float* __restrict__ q,
                const float* __restrict__ k, float* __restrict__ wq,
                float* __restrict__ wk)
{
  int r = blockIdx.x;
  int t = threadIdx.x;
  const float* Wr = W + (size_t)r * 128 * 128 + (size_t)t * 128;
  float aq = 0.f, ak = 0.f;
  for (int o = 0; o < 128; o++) {
    float w = Wr[o];
    aq = fmaf(w, q[o], aq);
    ak = fmaf(w, k[o], ak);
  }
  wq[r * 128 + t] = aq;
  wk[r * 128 + t] = ak;
}

__global__ __launch_bounds__(256)
void qdkd_kernel(const float* __restrict__ Xf, const float* __restrict__ wq,
                 const float* __restrict__ wk, float* __restrict__ QD,
                 float* __restrict__ KD)
{
  __shared__ float sq[NREL * 128], sk[NREL * 128];
  for (int i = threadIdx.x; i < NREL * 128; i += 256) { sq[i] = wq[i]; sk[i] = wk[i]; }
  __syncthreads();
  int n = blockIdx.x * 256 + threadIdx.x;
  if (n >= N_TOTAL) return;
  float aq[NREL], ak[NREL];
  #pragma unroll
  for (int r = 0; r < NREL; r++) { aq[r] = 0.f; ak[r] = 0.f; }
  for (int kc = 0; kc < 128; kc += 4) {
    float4 x = *(const float4*)&Xf[(size_t)n * 128 + kc];
    #pragma unroll
    for (int r = 0; r < NREL; r++) {
      aq[r] += x.x * sq[r * 128 + kc] + x.y * sq[r * 128 + kc + 1]
             + x.z * sq[r * 128 + kc + 2] + x.w * sq[r * 128 + kc + 3];
      ak[r] += x.x * sk[r * 128 + kc] + x.y * sk[r * 128 + kc + 1]
             + x.z * sk[r * 128 + kc + 2] + x.w * sk[r * 128 + kc + 3];
    }
  }
  #pragma unroll
  for (int r = 0; r < NREL; r++) {
    QD[(size_t)r * N_TOTAL + n] = aq[r];
    KD[(size_t)r * N_TOTAL + n] = ak[r];
  }
}

// ---------------------------------------------------------------------------
// CSR build; edge_fill writes CSR-ordered packed meta: src | (t<<15)
// ---------------------------------------------------------------------------
__global__ __launch_bounds__(256)
void edge_count(const int* __restrict__ dst, int* __restrict__ cnt) {
  int e = blockIdx.x * 256 + threadIdx.x;
  if (e < NEDGE) atomicAdd(&cnt[dst[e]], 1);
}

__global__ __launch_bounds__(1024)
void scan_kernel(const int* __restrict__ cnt, int* __restrict__ off,
                 int* __restrict__ cur) {
  __shared__ int ps[1024];
  const int t = threadIdx.x;
  const int CH = (N_TOTAL + 1023) / 1024;
  const int base = t * CH;
  int s = 0;
  for (int i = 0; i < CH; i++) {
    int idx = base + i;
    if (idx < N_TOTAL) s += cnt[idx];
  }
  ps[t] = s;
  __syncthreads();
  for (int o = 1; o < 1024; o <<= 1) {
    int v = (t >= o) ? ps[t - o] : 0;
    __syncthreads();
    ps[t] += v;
    __syncthreads();
  }
  int run = ps[t] - s;
  for (int i = 0; i < CH; i++) {
    int idx = base + i;
    if (idx < N_TOTAL) {
      off[idx] = run; cur[idx] = run;
      run += cnt[idx];
    }
  }
  if (t == 1023) off[N_TOTAL] = run;
}

__global__ __launch_bounds__(256)
void edge_fill(const int* __restrict__ dst, const int* __restrict__ src,
               const int* __restrict__ et, int* __restrict__ cur,
               int* __restrict__ meta) {
  int e = blockIdx.x * 256 + threadIdx.x;
  if (e >= NEDGE) return;
  int p = atomicAdd(&cur[dst[e]], 1);
  meta[p] = src[e] | (et[e] << 15);
}

// ---------------------------------------------------------------------------
// Wave-per-destination attention + per-relation aggregation. No LDS, no
// barriers. agg[d][r][128] output.
// ---------------------------------------------------------------------------
__global__ __launch_bounds__(256)
void csr_aggw(const int* __restrict__ off, const int* __restrict__ meta,
              const float* __restrict__ qd, const float* __restrict__ kd,
              const float* __restrict__ xrow, float* __restrict__ agg)
{
  const int d = blockIdx.x * 4 + (threadIdx.x >> 6);
  const int lane = threadIdx.x & 63;
  if (d >= N_TOTAL) return;
  const int n0 = off[d];
  const int deg = off[d + 1] - n0;

  float2 accr[NREL];
  #pragma unroll
  for (int r = 0; r < NREL; r++) accr[r] = make_float2(0.f, 0.f);

  float qrow[NREL];
  #pragma unroll
  for (int r = 0; r < NREL; r++) qrow[r] = qd[r * N_TOTAL + d];

  if (deg > 0) {
    if (deg <= 64 * WCAP) {
      int mreg[WCAP];
      float areg[WCAP];
      const int nc = (deg + 63) >> 6;
      float lmax = -3.0e38f;
      #pragma unroll
      for (int c = 0; c < WCAP; c++) {
        mreg[c] = 0; areg[c] = -3.0e38f;
        int i = c * 64 + lane;
        if (c < nc && i < deg) {
          int mm = meta[n0 + i];
          int s_ = mm & 0x7FFF, t = mm >> 15;
          float a = qrow[t] + kd[t * N_TOTAL + s_];
          a = (a > 0.f) ? a : SLOPE * a;
          mreg[c] = mm; areg[c] = a;
          lmax = fmaxf(lmax, a);
        }
      }
      #pragma unroll
      for (int m = 32; m; m >>= 1) lmax = fmaxf(lmax, __shfl_xor(lmax, m));
      float lsum = 0.f;
      #pragma unroll
      for (int c = 0; c < WCAP; c++) {
        int i = c * 64 + lane;
        if (c < nc && i < deg) {
          areg[c] = expf(areg[c] - lmax);
          lsum += areg[c];
        }
      }
      #pragma unroll
      for (int m = 32; m; m >>= 1) lsum += __shfl_xor(lsum, m);
      const float scale = (float)deg / lsum;
      for (int i = 0; i < deg; i++) {
        int c = i >> 6, l = i & 63;
        float cf = 0.f; int mm = 0;
        #pragma unroll
        for (int cc = 0; cc < WCAP; cc++) {
          if (cc == c) { cf = __shfl(areg[cc], l); mm = __shfl(mreg[cc], l); }
        }
        cf *= scale;
        int s_ = mm & 0x7FFF, t = mm >> 15;
        float2 v = *(const float2*)&xrow[(size_t)s_ * 128 + lane * 2];
        float2 cv = make_float2(cf * v.x, cf * v.y);
        #pragma unroll
        for (int r = 0; r < NREL; r++) {
          bool hit = (t == r);
          accr[r].x += hit ? cv.x : 0.f;
          accr[r].y += hit ? cv.y : 0.f;
        }
      }
    } else {
      float m = -3.0e38f;
      for (int i = 0; i < deg; i++) {
        int mm = meta[n0 + i];
        int s_ = mm & 0x7FFF, t = mm >> 15;
        float a = qrow[t] + kd[t * N_TOTAL + s_];
        a = (a > 0.f) ? a : SLOPE * a;
        m = fmaxf(m, a);
      }
      float ssum = 0.f;
      for (int i = 0; i < deg; i++) {
        int mm = meta[n0 + i];
        int s_ = mm & 0x7FFF, t = mm >> 15;
        float a = qrow[t] + kd[t * N_TOTAL + s_];
        a = (a > 0.f) ? a : SLOPE * a;
        ssum += expf(a - m);
      }
      const float scale = (float)deg / ssum;
      for (int i = 0; i < deg; i++) {
        int mm = meta[n0 + i];
        int s_ = mm & 0x7FFF, t = mm >> 15;
        float a = qrow[t] + kd[t * N_TOTAL + s_];
        a = (a > 0.f) ? a : SLOPE * a;
        float cf = expf(a - m) * scale;
        float2 v = *(const float2*)&xrow[(size_t)s_ * 128 + lane * 2];
        float2 cv = make_float2(cf * v.x, cf * v.y);
        #pragma unroll
        for (int r = 0; r < NREL; r++) {
          bool hit = (t == r);
          accr[r].x += hit ? cv.x : 0.f;
          accr[r].y += hit ? cv.y : 0.f;
        }
      }
    }
  }
  #pragma unroll
  for (int r = 0; r < NREL; r++)
    *(float2*)&agg[((size_t)d * NREL + r) * 128 + lane * 2] = accr[r];
}

__global__ __launch_bounds__(256)
void lin2_kernel(const float* __restrict__ z, const float* __restrict__ W,
                 const float* __restrict__ b, float* __restrict__ out)
{
  int row = blockIdx.x * 4 + (threadIdx.x >> 6);
  int lane = threadIdx.x & 63;
  if (row >= NPER) return;
  float p[5] = {0.f, 0.f, 0.f, 0.f, 0.f};
  #pragma unroll
  for (int h = 0; h < 2; h++) {
    int kidx = lane + h * 64;
    float zv = z[(size_t)row * 128 + kidx];
    #pragma unroll
    for (int j = 0; j < 5; j++) p[j] = fmaf(zv, W[kidx * 5 + j], p[j]);
  }
  #pragma unroll
  for (int mm = 32; mm; mm >>= 1)
    #pragma unroll
    for (int j = 0; j < 5; j++) p[j] += __shfl_xor(p[j], mm);
  if (lane == 0) {
    #pragma unroll
    for (int j = 0; j < 5; j++) out[(size_t)row * 5 + j] = p[j] + b[j];
  }
}

// ---------------------------------------------------------------------------
extern "C" void kernel_launch(void* const* d_in, const int* in_sizes, int n_in,
                              void* d_out, int out_size, void* d_ws, size_t ws_size,
                              hipStream_t stream) {
  const float* xs[3] = {(const float*)d_in[0], (const float*)d_in[1], (const float*)d_in[2]};
  const float* projW[3] = {(const float*)d_in[3], (const float*)d_in[5], (const float*)d_in[7]};
  const float* projb[3] = {(const float*)d_in[4], (const float*)d_in[6], (const float*)d_in[8]};
  const float* slW[3]   = {(const float*)d_in[9], (const float*)d_in[11], (const float*)d_in[13]};
  const float* slb[3]   = {(const float*)d_in[10], (const float*)d_in[12], (const float*)d_in[14]};
  const float* W1 = (const float*)d_in[15];
  const float* q1 = (const float*)d_in[16];
  const float* k1 = (const float*)d_in[17];
  const float* b1 = (const float*)d_in[18];
  const float* W2 = (const float*)d_in[19];
  const float* q2 = (const float*)d_in[20];
  const float* k2 = (const float*)d_in[21];
  const float* b2 = (const float*)d_in[22];
  const float* lin1W = (const float*)d_in[23];
  const float* lin1b = (const float*)d_in[24];
  const float* lin2W = (const float*)d_in[25];
  const float* lin2b = (const float*)d_in[26];
  const int* esrc = (const int*)d_in[27];
  const int* edst = (const int*)d_in[28];
  const int* etyp = (const int*)d_in[29];

  char* wp = (char*)d_ws;
  auto alloc = [&](size_t bytes) -> char* {
    char* p = wp; wp += (bytes + 255) & ~(size_t)255; return p;
  };
  float* Xf  = (float*)alloc((size_t)N_TOTAL * 128 * 4);
  float* SL  = (float*)alloc((size_t)N_TOTAL * 128 * 4);
  float* Hf  = (float*)alloc((size_t)N_TOTAL * 128 * 4);
  float* QD  = (float*)alloc((size_t)NREL * N_TOTAL * 4);
  float* KD  = (float*)alloc((size_t)NREL * N_TOTAL * 4);
  float* Z   = (float*)alloc((size_t)NPER * 128 * 4);
  float* WQ1 = (float*)alloc((size_t)NREL * 128 * 4);
  float* WK1 = (float*)alloc((size_t)NREL * 128 * 4);
  float* WQ2 = (float*)alloc((size_t)NREL * 128 * 4);
  float* WK2 = (float*)alloc((size_t)NREL * 128 * 4);
  int*   CNT = (int*)  alloc((size_t)N_TOTAL * 4);
  int*   OFF = (int*)  alloc((size_t)(N_TOTAL + 1) * 4);
  int*   CUR = (int*)  alloc((size_t)N_TOTAL * 4);
  int*   META= (int*)  alloc((size_t)NEDGE * 4);

  // PART region (61.4 MB): proj partials [3][4][NPER][128] f32.
  float* PART = (float*)alloc((size_t)3 * 4 * NPER * 128 * 4);
  // AGG [30000][768] f32 (92 MB)
  float* AGG  = (float*)alloc((size_t)N_TOTAL * NREL * 128 * 4);

  CW cw;
  int nW = 0;
  auto addW = [&](const float* src, int K) {
    int Kp = (K + 63) & ~63;
    cw.src[nW] = src; cw.K[nW] = K; cw.Kp[nW] = Kp;
    cw.dst[nW] = (u16*)alloc((size_t)128 * Kp * 2);
    nW++;
  };
  addW(projW[0], 2000); addW(projW[1], 1500); addW(projW[2], 1000);  // 0-2
  addW(slW[0], 128); addW(slW[1], 128); addW(slW[2], 128);           // 3-5
  addW(W1, NREL * 128);   // 6: stacked [768][128] -> Bt [128][768]
  addW(W2, NREL * 128);   // 7
  addW(lin1W, 128);       // 8

  const int gridM_per = (NPER + 63) / 64;     // 157
  const int gridM_tot = (N_TOTAL + 63) / 64;  // 469
  const int gridE = (NEDGE + 255) / 256;

  // ---- CSR build ----
  hipMemsetAsync(CNT, 0, (size_t)N_TOTAL * 4, stream);
  edge_count<<<gridE, 256, 0, stream>>>(edst, CNT);
  scan_kernel<<<1, 1024, 0, stream>>>(CNT, OFF, CUR);
  edge_fill<<<gridE, 256, 0, stream>>>(edst, esrc, etyp, CUR, META);

  conv_w<<<dim3(1024, 1, 9), 256, 0, stream>>>(cw);
  wqk_kernel<<<NREL, 128, 0, stream>>>(W1, q1, k1, WQ1, WK1);
  wqk_kernel<<<NREL, 128, 0, stream>>>(W2, q2, k2, WQ2, WK2);

  // ---- projections via split-K (chunks of 512 — r6-proven) ----
  {
    SK sk;
    for (int z = 0; z < 3; z++) {
      sk.A[z] = xs[z]; sk.Bt[z] = cw.dst[z];
      sk.C[z] = PART + (size_t)z * 4 * NPER * 128;
      sk.K[z] = cw.K[z]; sk.Kp[z] = cw.Kp[z];
    }
    gemm_splitk<<<dim3(gridM_per, 4, 3), 256, 0, stream>>>(sk, NPER, 512);
    RP rp;
    for (int z = 0; z < 3; z++) { rp.bias[z] = projb[z]; rp.nch[z] = cw.Kp[z] / 512; }
    reduce_proj<<<dim3(NPER * 128 / 256, 1, 3), 256, 0, stream>>>(PART, rp, Xf);
  }
  // ---- self-loops: SL = Xf_i @ slW_i + slb_i ----
  {
    GB g;
    for (int z = 0; z < 3; z++) {
      g.A[z] = Xf + (size_t)z * NPER * 128; g.Bt[z] = cw.dst[3 + z];
      g.bias[z] = slb[z]; g.add[z] = nullptr;
      g.C[z] = SL + (size_t)z * NPER * 128;
      g.K[z] = 128; g.Kp[z] = 128;
    }
    gemm_mfma<true, false, false><<<dim3(gridM_per, 1, 3), 256, 0, stream>>>(g, NPER);
  }

  for (int layer = 0; layer < 2; layer++) {
    const float* Ain = (layer == 0) ? Xf : Hf;
    const float* WQ = (layer == 0) ? WQ1 : WQ2;
    const float* WK = (layer == 0) ? WK1 : WK2;
    const float* bb = (layer == 0) ? b1 : b2;
    const u16* Wstk = cw.dst[6 + layer];

    qdkd_kernel<<<(N_TOTAL + 255) / 256, 256, 0, stream>>>(Ain, WQ, WK, QD, KD);
    csr_aggw<<<(N_TOTAL + 3) / 4, 256, 0, stream>>>(OFF, META, QD, KD, Ain, AGG);
    // transform: Hf = elu(AGG[30000,768] @ Wstack[768,128] + b + SL), fused
    GB g;
    g.A[0] = AGG; g.Bt[0] = Wstk; g.bias[0] = bb; g.add[0] = SL; g.C[0] = Hf;
    g.K[0] = NREL * 128; g.Kp[0] = NREL * 128;
    gemm_mfma<true, true, true><<<dim3(gridM_tot, 1, 1), 256, 0, stream>>>(g, N_TOTAL);
  }

  // ---- head ----
  {
    GB g;
    g.A[0] = Hf; g.Bt[0] = cw.dst[8]; g.bias[0] = lin1b; g.add[0] = nullptr; g.C[0] = Z;
    g.K[0] = 128; g.Kp[0] = 128;
    gemm_mfma<true, true, false><<<dim3(gridM_per, 1, 1), 256, 0, stream>>>(g, NPER);
  }
  lin2_kernel<<<(NPER + 3) / 4, 256, 0, stream>>>(Z, lin2W, lin2b, (float*)d_out);
}

// Round 14
// 435.402 us; speedup vs baseline: 1.0310x; 1.0172x over previous
//
#include <hip/hip_runtime.h>
#include <math.h>

#define N_TOTAL 30000
#define NPER 10000
#define NEDGE 500000
#define NREL 6
#define SLOPE 0.2f
#define WCAP 4        // register edge capacity per lane (4*64 = 256 edges/wave)

typedef __attribute__((ext_vector_type(4))) float f32x4;
typedef __attribute__((ext_vector_type(8))) short s16x8;
typedef __attribute__((ext_vector_type(4))) short s16x4;
typedef unsigned short u16;
typedef unsigned int u32;

__device__ __forceinline__ u16 f2bf(float v) {
  u32 x = __float_as_uint(v);
  u32 r = (x + 0x7fffu + ((x >> 16) & 1u)) >> 16;  // RNE
  return (u16)r;
}
__device__ __forceinline__ float bf2f(u16 u) {
  return __uint_as_float(((u32)u) << 16);
}

// ---------------------------------------------------------------------------
// Split-precision bf16 MFMA GEMM core (r6-proven schedule), depth-1 prefetch:
//   prologue: LOAD(t0) -> regs
//   loop: {WRITE(regs->LDS); barrier; LOAD(t+1); ds_read+MFMA; barrier}
// Templated on MI (rows of 16x16 frags per wave): BM = 32*MI.
//   MI=2: BM=64 (r6 config, proj/SL/head).  MI=1: BM=32 (transform — 2x
//   blocks for TLP; B re-reads are L2-resident so HBM traffic unchanged).
// All staging geometry derived from MI (no hand-copied loops — r10 lesson).
// A staged f32 -> hi/lo bf16 (2 MFMAs/frag): only weight rounding remains.
// BN=128, BK=64. 256 thr = 4 waves (2x2), wave tile (16*MI)x64.
// LDS: As/Aslo BM*128 B each + Bs 16 KB.  XOR-swizzle byte ^= (row&7)<<4
// (measured 0 conflicts). C/D frag: col=lane&15, row=(lane>>4)*4+reg.
// ---------------------------------------------------------------------------
template<int MI, bool BIAS, bool ELU, bool ADD, bool RAW>
__device__ __forceinline__ void gemm_core(
    const float* __restrict__ A, const u16* __restrict__ Bt,
    const float* __restrict__ bias, const float* __restrict__ add,
    float* __restrict__ C, int M, int K, int Kp, int kbeg, int kend)
{
  constexpr int BM = 32 * MI;
  __shared__ char As[BM * 128];
  __shared__ char Aslo[BM * 128];
  __shared__ char Bs[128 * 128];
  const int tid = threadIdx.x;
  const int bm = blockIdx.x * BM;
  const int lane = tid & 63;
  const int wave = tid >> 6;
  const int wr = wave >> 1, wc = wave & 1;
  const int lane16 = lane & 15, lhalf = lane >> 4;

  const int a_row0 = tid >> 4;            // + it*16 (it<2*MI -> rows 0..BM-1)
  const int a_kc = (tid & 15) << 2;
  const int b_row0 = tid >> 3;            // + it*32 (it<4 -> rows 0..127)
  const int b_kc = (tid & 7) << 3;

  float4 pa[2 * MI];
  s16x8 pb[4];

  auto LOAD = [&](int k0) {
    #pragma unroll
    for (int it = 0; it < 2 * MI; it++) {
      int gr = bm + a_row0 + it * 16, gk = k0 + a_kc;
      float4 v = make_float4(0.f, 0.f, 0.f, 0.f);
      if (gr < M && gk < K) v = *(const float4*)&A[(size_t)gr * K + gk];
      pa[it] = v;
    }
    #pragma unroll
    for (int it = 0; it < 4; it++) {
      int row = b_row0 + it * 32;
      pb[it] = *(const s16x8*)&Bt[(size_t)row * Kp + k0 + b_kc];
    }
  };

  auto WRITE = [&]() {
    #pragma unroll
    for (int it = 0; it < 2 * MI; it++) {
      int row = a_row0 + it * 16;
      float vv[4] = {pa[it].x, pa[it].y, pa[it].z, pa[it].w};
      s16x4 hi, lo;
      #pragma unroll
      for (int j = 0; j < 4; j++) {
        u16 h = f2bf(vv[j]);
        hi[j] = (short)h;
        lo[j] = (short)f2bf(vv[j] - bf2f(h));
      }
      int boff = row * 128 + ((a_kc * 2) ^ ((row & 7) << 4));
      *(s16x4*)(As + boff) = hi;
      *(s16x4*)(Aslo + boff) = lo;
    }
    #pragma unroll
    for (int it = 0; it < 4; it++) {
      int row = b_row0 + it * 32;
      *(s16x8*)(Bs + row * 128 + ((b_kc * 2) ^ ((row & 7) << 4))) = pb[it];
    }
  };

  f32x4 acc[MI][4];
  #pragma unroll
  for (int mi = 0; mi < MI; mi++)
    #pragma unroll
    for (int ni = 0; ni < 4; ni++)
      #pragma unroll
      for (int q = 0; q < 4; q++) acc[mi][ni][q] = 0.f;

  auto MFMA_STEP = [&]() {
    #pragma unroll
    for (int kk = 0; kk < 2; kk++) {
      const int kbyte = kk * 64 + lhalf * 16;
      s16x8 afh[MI], afl[MI], bfr[4];
      #pragma unroll
      for (int mi = 0; mi < MI; mi++) {
        int row = wr * (16 * MI) + mi * 16 + lane16;
        int boff = row * 128 + (kbyte ^ ((row & 7) << 4));
        afh[mi] = *(const s16x8*)(As + boff);
        afl[mi] = *(const s16x8*)(Aslo + boff);
      }
      #pragma unroll
      for (int ni = 0; ni < 4; ni++) {
        int row = wc * 64 + ni * 16 + lane16;
        bfr[ni] = *(const s16x8*)(Bs + row * 128 + (kbyte ^ ((row & 7) << 4)));
      }
      #pragma unroll
      for (int mi = 0; mi < MI; mi++)
        #pragma unroll
        for (int ni = 0; ni < 4; ni++) {
          acc[mi][ni] = __builtin_amdgcn_mfma_f32_16x16x32_bf16(
              afl[mi], bfr[ni], acc[mi][ni], 0, 0, 0);
          acc[mi][ni] = __builtin_amdgcn_mfma_f32_16x16x32_bf16(
              afh[mi], bfr[ni], acc[mi][ni], 0, 0, 0);
        }
    }
  };

  const int nt = (kend - kbeg) >> 6;
  LOAD(kbeg);
  for (int t = 0; t < nt; t++) {
    WRITE();
    __syncthreads();
    if (t + 1 < nt) LOAD(kbeg + (t + 1) * 64);
    MFMA_STEP();
    __syncthreads();
  }

  float bcol[4];
  #pragma unroll
  for (int ni = 0; ni < 4; ni++) {
    int col = wc * 64 + ni * 16 + lane16;
    if (BIAS) bcol[ni] = bias[col];
  }
  #pragma unroll
  for (int mi = 0; mi < MI; mi++) {
    #pragma unroll
    for (int q = 0; q < 4; q++) {
      int grow = bm + wr * (16 * MI) + mi * 16 + lhalf * 4 + q;
      if (grow < M) {
        #pragma unroll
        for (int ni = 0; ni < 4; ni++) {
          float v = acc[mi][ni][q];
          int col = wc * 64 + ni * 16 + lane16;
          if (BIAS) v += bcol[ni];
          if (ADD) v += add[(size_t)grow * 128 + col];
          if (!RAW && ELU) v = v > 0.f ? v : expm1f(v);
          C[(size_t)grow * 128 + col] = v;
        }
      }
    }
  }
}

struct GB {
  const float* A[3];
  const u16* Bt[3];
  const float* bias[3];
  const float* add[3];
  float* C[3];
  int K[3];
  int Kp[3];
};

template<int MI, bool BIAS, bool ELU, bool ADD>
__global__ __launch_bounds__(256, 2)
void gemm_mfma(GB gb, int M)
{
  int z = blockIdx.z;
  gemm_core<MI, BIAS, ELU, ADD, false>(gb.A[z], gb.Bt[z], gb.bias[z], gb.add[z],
                                       gb.C[z], M, gb.K[z], gb.Kp[z], 0, gb.Kp[z]);
}

struct SK {
  const float* A[3];
  const u16* Bt[3];
  float* C[3];          // partial base per z: + chunk_idx*M*128
  int K[3];
  int Kp[3];
};

__global__ __launch_bounds__(256, 2)
void gemm_splitk(SK sk, int M, int chunk)
{
  int z = blockIdx.z;
  int cb = blockIdx.y * chunk;
  if (cb >= sk.Kp[z]) return;
  int kend = (cb + chunk < sk.Kp[z]) ? cb + chunk : sk.Kp[z];
  float* C = sk.C[z] + (size_t)blockIdx.y * M * 128;
  gemm_core<2, false, false, false, true>(sk.A[z], sk.Bt[z], nullptr, nullptr,
                                          C, M, sk.K[z], sk.Kp[z], cb, kend);
}

struct RP { const float* bias[3]; int nch[3]; };

__global__ __launch_bounds__(256)
void reduce_proj(const float* __restrict__ part, RP rp, float* __restrict__ Xf)
{
  int z = blockIdx.z;
  int i = blockIdx.x * 256 + threadIdx.x;   // over NPER*128
  int c = i & 127;
  int nch = rp.nch[z];
  const float* base = part + (size_t)z * 4 * NPER * 128 + i;
  float s = 0.f;
  for (int ch = 0; ch < nch; ch++) s += base[(size_t)ch * NPER * 128];
  s += rp.bias[z][c];
  Xf[(size_t)z * NPER * 128 + i] = s > 0.f ? s : expm1f(s);
}

// ---------------------------------------------------------------------------
// Weight convert: src f32 [K][128] -> dst bf16 [128][Kp] (transposed, padded)
// ---------------------------------------------------------------------------
struct CW {
  const float* src[9];
  u16* dst[9];
  int K[9];
  int Kp[9];
};

__global__ __launch_bounds__(256)
void conv_w(CW cw) {
  int z = blockIdx.z;
  int K = cw.K[z], Kp = cw.Kp[z];
  int idx = blockIdx.x * 256 + threadIdx.x;
  if (idx >= 128 * Kp) return;
  int kq = idx >> 7, n = idx & 127;
  cw.dst[z][(size_t)n * Kp + kq] =
      (kq < K) ? f2bf(cw.src[z][(size_t)kq * 128 + n]) : (u16)0;
}

// ---------------------------------------------------------------------------
// Attention-score precompute (exact f32): Wq[r]=W[r]@q; QD[r,n]=X[n,:].Wq[r]
// ---------------------------------------------------------------------------
__global__ __launch_bounds__(128)
void wqk_kernel(const float* __restrict__ W, const float* __restrict__ q,
                const float* __restrict__ k, float* __restrict__ wq,
                float* __restrict__ wk)
{
  int r = blockIdx.x;
  int t = threadIdx.x;
  const float* Wr = W + (size_t)r * 128 * 128 + (size_t)t * 128;
  float aq = 0.f, ak = 0.f;
  for (int o = 0; o < 128; o++) {
    float w = Wr[o];
    aq = fmaf(w, q[o], aq);
    ak = fmaf(w, k[o], ak);
  }
  wq[r * 128 + t] = aq;
  wk[r * 128 + t] = ak;
}

__global__ __launch_bounds__(256)
void qdkd_kernel(const float* __restrict__ Xf, const float* __restrict__ wq,
                 const float* __restrict__ wk, float* __restrict__ QD,
                 float* __restrict__ KD)
{
  __shared__ float sq[NREL * 128], sk[NREL * 128];
  for (int i = threadIdx.x; i < NREL * 128; i += 256) { sq[i] = wq[i]; sk[i] = wk[i]; }
  __syncthreads();
  int n = blockIdx.x * 256 + threadIdx.x;
  if (n >= N_TOTAL) return;
  float aq[NREL], ak[NREL];
  #pragma unroll
  for (int r = 0; r < NREL; r++) { aq[r] = 0.f; ak[r] = 0.f; }
  for (int kc = 0; kc < 128; kc += 4) {
    float4 x = *(const float4*)&Xf[(size_t)n * 128 + kc];
    #pragma unroll
    for (int r = 0; r < NREL; r++) {
      aq[r] += x.x * sq[r * 128 + kc] + x.y * sq[r * 128 + kc + 1]
             + x.z * sq[r * 128 + kc + 2] + x.w * sq[r * 128 + kc + 3];
      ak[r] += x.x * sk[r * 128 + kc] + x.y * sk[r * 128 + kc + 1]
             + x.z * sk[r * 128 + kc + 2] + x.w * sk[r * 128 + kc + 3];
    }
  }
  #pragma unroll
  for (int r = 0; r < NREL; r++) {
    QD[(size_t)r * N_TOTAL + n] = aq[r];
    KD[(size_t)r * N_TOTAL + n] = ak[r];
  }
}

// ---------------------------------------------------------------------------
// CSR build; edge_fill writes CSR-ordered packed meta: src | (t<<15)
// ---------------------------------------------------------------------------
__global__ __launch_bounds__(256)
void edge_count(const int* __restrict__ dst, int* __restrict__ cnt) {
  int e = blockIdx.x * 256 + threadIdx.x;
  if (e < NEDGE) atomicAdd(&cnt[dst[e]], 1);
}

__global__ __launch_bounds__(1024)
void scan_kernel(const int* __restrict__ cnt, int* __restrict__ off,
                 int* __restrict__ cur) {
  __shared__ int ps[1024];
  const int t = threadIdx.x;
  const int CH = (N_TOTAL + 1023) / 1024;
  const int base = t * CH;
  int s = 0;
  for (int i = 0; i < CH; i++) {
    int idx = base + i;
    if (idx < N_TOTAL) s += cnt[idx];
  }
  ps[t] = s;
  __syncthreads();
  for (int o = 1; o < 1024; o <<= 1) {
    int v = (t >= o) ? ps[t - o] : 0;
    __syncthreads();
    ps[t] += v;
    __syncthreads();
  }
  int run = ps[t] - s;
  for (int i = 0; i < CH; i++) {
    int idx = base + i;
    if (idx < N_TOTAL) {
      off[idx] = run; cur[idx] = run;
      run += cnt[idx];
    }
  }
  if (t == 1023) off[N_TOTAL] = run;
}

__global__ __launch_bounds__(256)
void edge_fill(const int* __restrict__ dst, const int* __restrict__ src,
               const int* __restrict__ et, int* __restrict__ cur,
               int* __restrict__ meta) {
  int e = blockIdx.x * 256 + threadIdx.x;
  if (e >= NEDGE) return;
  int p = atomicAdd(&cur[dst[e]], 1);
  meta[p] = src[e] | (et[e] << 15);
}

// ---------------------------------------------------------------------------
// Wave-per-destination attention + per-relation aggregation. No LDS, no
// barriers. agg[d][r][128] output.
// ---------------------------------------------------------------------------
__global__ __launch_bounds__(256)
void csr_aggw(const int* __restrict__ off, const int* __restrict__ meta,
              const float* __restrict__ qd, const float* __restrict__ kd,
              const float* __restrict__ xrow, float* __restrict__ agg)
{
  const int d = blockIdx.x * 4 + (threadIdx.x >> 6);
  const int lane = threadIdx.x & 63;
  if (d >= N_TOTAL) return;
  const int n0 = off[d];
  const int deg = off[d + 1] - n0;

  float2 accr[NREL];
  #pragma unroll
  for (int r = 0; r < NREL; r++) accr[r] = make_float2(0.f, 0.f);

  float qrow[NREL];
  #pragma unroll
  for (int r = 0; r < NREL; r++) qrow[r] = qd[r * N_TOTAL + d];

  if (deg > 0) {
    if (deg <= 64 * WCAP) {
      int mreg[WCAP];
      float areg[WCAP];
      const int nc = (deg + 63) >> 6;
      float lmax = -3.0e38f;
      #pragma unroll
      for (int c = 0; c < WCAP; c++) {
        mreg[c] = 0; areg[c] = -3.0e38f;
        int i = c * 64 + lane;
        if (c < nc && i < deg) {
          int mm = meta[n0 + i];
          int s_ = mm & 0x7FFF, t = mm >> 15;
          float a = qrow[t] + kd[t * N_TOTAL + s_];
          a = (a > 0.f) ? a : SLOPE * a;
          mreg[c] = mm; areg[c] = a;
          lmax = fmaxf(lmax, a);
        }
      }
      #pragma unroll
      for (int m = 32; m; m >>= 1) lmax = fmaxf(lmax, __shfl_xor(lmax, m));
      float lsum = 0.f;
      #pragma unroll
      for (int c = 0; c < WCAP; c++) {
        int i = c * 64 + lane;
        if (c < nc && i < deg) {
          areg[c] = expf(areg[c] - lmax);
          lsum += areg[c];
        }
      }
      #pragma unroll
      for (int m = 32; m; m >>= 1) lsum += __shfl_xor(lsum, m);
      const float scale = (float)deg / lsum;
      for (int i = 0; i < deg; i++) {
        int c = i >> 6, l = i & 63;
        float cf = 0.f; int mm = 0;
        #pragma unroll
        for (int cc = 0; cc < WCAP; cc++) {
          if (cc == c) { cf = __shfl(areg[cc], l); mm = __shfl(mreg[cc], l); }
        }
        cf *= scale;
        int s_ = mm & 0x7FFF, t = mm >> 15;
        float2 v = *(const float2*)&xrow[(size_t)s_ * 128 + lane * 2];
        float2 cv = make_float2(cf * v.x, cf * v.y);
        #pragma unroll
        for (int r = 0; r < NREL; r++) {
          bool hit = (t == r);
          accr[r].x += hit ? cv.x : 0.f;
          accr[r].y += hit ? cv.y : 0.f;
        }
      }
    } else {
      float m = -3.0e38f;
      for (int i = 0; i < deg; i++) {
        int mm = meta[n0 + i];
        int s_ = mm & 0x7FFF, t = mm >> 15;
        float a = qrow[t] + kd[t * N_TOTAL + s_];
        a = (a > 0.f) ? a : SLOPE * a;
        m = fmaxf(m, a);
      }
      float ssum = 0.f;
      for (int i = 0; i < deg; i++) {
        int mm = meta[n0 + i];
        int s_ = mm & 0x7FFF, t = mm >> 15;
        float a = qrow[t] + kd[t * N_TOTAL + s_];
        a = (a > 0.f) ? a : SLOPE * a;
        ssum += expf(a - m);
      }
      const float scale = (float)deg / ssum;
      for (int i = 0; i < deg; i++) {
        int mm = meta[n0 + i];
        int s_ = mm & 0x7FFF, t = mm >> 15;
        float a = qrow[t] + kd[t * N_TOTAL + s_];
        a = (a > 0.f) ? a : SLOPE * a;
        float cf = expf(a - m) * scale;
        float2 v = *(const float2*)&xrow[(size_t)s_ * 128 + lane * 2];
        float2 cv = make_float2(cf * v.x, cf * v.y);
        #pragma unroll
        for (int r = 0; r < NREL; r++) {
          bool hit = (t == r);
          accr[r].x += hit ? cv.x : 0.f;
          accr[r].y += hit ? cv.y : 0.f;
        }
      }
    }
  }
  #pragma unroll
  for (int r = 0; r < NREL; r++)
    *(float2*)&agg[((size_t)d * NREL + r) * 128 + lane * 2] = accr[r];
}

__global__ __launch_bounds__(256)
void lin2_kernel(const float* __restrict__ z, const float* __restrict__ W,
                 const float* __restrict__ b, float* __restrict__ out)
{
  int row = blockIdx.x * 4 + (threadIdx.x >> 6);
  int lane = threadIdx.x & 63;
  if (row >= NPER) return;
  float p[5] = {0.f, 0.f, 0.f, 0.f, 0.f};
  #pragma unroll
  for (int h = 0; h < 2; h++) {
    int kidx = lane + h * 64;
    float zv = z[(size_t)row * 128 + kidx];
    #pragma unroll
    for (int j = 0; j < 5; j++) p[j] = fmaf(zv, W[kidx * 5 + j], p[j]);
  }
  #pragma unroll
  for (int mm = 32; mm; mm >>= 1)
    #pragma unroll
    for (int j = 0; j < 5; j++) p[j] += __shfl_xor(p[j], mm);
  if (lane == 0) {
    #pragma unroll
    for (int j = 0; j < 5; j++) out[(size_t)row * 5 + j] = p[j] + b[j];
  }
}

// ---------------------------------------------------------------------------
extern "C" void kernel_launch(void* const* d_in, const int* in_sizes, int n_in,
                              void* d_out, int out_size, void* d_ws, size_t ws_size,
                              hipStream_t stream) {
  const float* xs[3] = {(const float*)d_in[0], (const float*)d_in[1], (const float*)d_in[2]};
  const float* projW[3] = {(const float*)d_in[3], (const float*)d_in[5], (const float*)d_in[7]};
  const float* projb[3] = {(const float*)d_in[4], (const float*)d_in[6], (const float*)d_in[8]};
  const float* slW[3]   = {(const float*)d_in[9], (const float*)d_in[11], (const float*)d_in[13]};
  const float* slb[3]   = {(const float*)d_in[10], (const float*)d_in[12], (const float*)d_in[14]};
  const float* W1 = (const float*)d_in[15];
  const float* q1 = (const float*)d_in[16];
  const float* k1 = (const float*)d_in[17];
  const float* b1 = (const float*)d_in[18];
  const float* W2 = (const float*)d_in[19];
  const float* q2 = (const float*)d_in[20];
  const float* k2 = (const float*)d_in[21];
  const float* b2 = (const float*)d_in[22];
  const float* lin1W = (const float*)d_in[23];
  const float* lin1b = (const float*)d_in[24];
  const float* lin2W = (const float*)d_in[25];
  const float* lin2b = (const float*)d_in[26];
  const int* esrc = (const int*)d_in[27];
  const int* edst = (const int*)d_in[28];
  const int* etyp = (const int*)d_in[29];

  char* wp = (char*)d_ws;
  auto alloc = [&](size_t bytes) -> char* {
    char* p = wp; wp += (bytes + 255) & ~(size_t)255; return p;
  };
  float* Xf  = (float*)alloc((size_t)N_TOTAL * 128 * 4);
  float* SL  = (float*)alloc((size_t)N_TOTAL * 128 * 4);
  float* Hf  = (float*)alloc((size_t)N_TOTAL * 128 * 4);
  float* QD  = (float*)alloc((size_t)NREL * N_TOTAL * 4);
  float* KD  = (float*)alloc((size_t)NREL * N_TOTAL * 4);
  float* Z   = (float*)alloc((size_t)NPER * 128 * 4);
  float* WQ1 = (float*)alloc((size_t)NREL * 128 * 4);
  float* WK1 = (float*)alloc((size_t)NREL * 128 * 4);
  float* WQ2 = (float*)alloc((size_t)NREL * 128 * 4);
  float* WK2 = (float*)alloc((size_t)NREL * 128 * 4);
  int*   CNT = (int*)  alloc((size_t)N_TOTAL * 4);
  int*   OFF = (int*)  alloc((size_t)(N_TOTAL + 1) * 4);
  int*   CUR = (int*)  alloc((size_t)N_TOTAL * 4);
  int*   META= (int*)  alloc((size_t)NEDGE * 4);

  // PART region (61.4 MB): proj partials [3][4][NPER][128] f32.
  float* PART = (float*)alloc((size_t)3 * 4 * NPER * 128 * 4);
  // AGG [30000][768] f32 (92 MB)
  float* AGG  = (float*)alloc((size_t)N_TOTAL * NREL * 128 * 4);

  CW cw;
  int nW = 0;
  auto addW = [&](const float* src, int K) {
    int Kp = (K + 63) & ~63;
    cw.src[nW] = src; cw.K[nW] = K; cw.Kp[nW] = Kp;
    cw.dst[nW] = (u16*)alloc((size_t)128 * Kp * 2);
    nW++;
  };
  addW(projW[0], 2000); addW(projW[1], 1500); addW(projW[2], 1000);  // 0-2
  addW(slW[0], 128); addW(slW[1], 128); addW(slW[2], 128);           // 3-5
  addW(W1, NREL * 128);   // 6: stacked [768][128] -> Bt [128][768]
  addW(W2, NREL * 128);   // 7
  addW(lin1W, 128);       // 8

  const int gridM_per = (NPER + 63) / 64;      // 157 (BM=64)
  const int gridM_t32 = (N_TOTAL + 31) / 32;   // 938 (BM=32, transform)
  const int gridE = (NEDGE + 255) / 256;

  // ---- CSR build ----
  hipMemsetAsync(CNT, 0, (size_t)N_TOTAL * 4, stream);
  edge_count<<<gridE, 256, 0, stream>>>(edst, CNT);
  scan_kernel<<<1, 1024, 0, stream>>>(CNT, OFF, CUR);
  edge_fill<<<gridE, 256, 0, stream>>>(edst, esrc, etyp, CUR, META);

  conv_w<<<dim3(1024, 1, 9), 256, 0, stream>>>(cw);
  wqk_kernel<<<NREL, 128, 0, stream>>>(W1, q1, k1, WQ1, WK1);
  wqk_kernel<<<NREL, 128, 0, stream>>>(W2, q2, k2, WQ2, WK2);

  // ---- projections via split-K (chunks of 512 — r6-proven) ----
  {
    SK sk;
    for (int z = 0; z < 3; z++) {
      sk.A[z] = xs[z]; sk.Bt[z] = cw.dst[z];
      sk.C[z] = PART + (size_t)z * 4 * NPER * 128;
      sk.K[z] = cw.K[z]; sk.Kp[z] = cw.Kp[z];
    }
    gemm_splitk<<<dim3(gridM_per, 4, 3), 256, 0, stream>>>(sk, NPER, 512);
    RP rp;
    for (int z = 0; z < 3; z++) { rp.bias[z] = projb[z]; rp.nch[z] = cw.Kp[z] / 512; }
    reduce_proj<<<dim3(NPER * 128 / 256, 1, 3), 256, 0, stream>>>(PART, rp, Xf);
  }
  // ---- self-loops: SL = Xf_i @ slW_i + slb_i (BM=64) ----
  {
    GB g;
    for (int z = 0; z < 3; z++) {
      g.A[z] = Xf + (size_t)z * NPER * 128; g.Bt[z] = cw.dst[3 + z];
      g.bias[z] = slb[z]; g.add[z] = nullptr;
      g.C[z] = SL + (size_t)z * NPER * 128;
      g.K[z] = 128; g.Kp[z] = 128;
    }
    gemm_mfma<2, true, false, false><<<dim3(gridM_per, 1, 3), 256, 0, stream>>>(g, NPER);
  }

  for (int layer = 0; layer < 2; layer++) {
    const float* Ain = (layer == 0) ? Xf : Hf;
    const float* WQ = (layer == 0) ? WQ1 : WQ2;
    const float* WK = (layer == 0) ? WK1 : WK2;
    const float* bb = (layer == 0) ? b1 : b2;
    const u16* Wstk = cw.dst[6 + layer];

    qdkd_kernel<<<(N_TOTAL + 255) / 256, 256, 0, stream>>>(Ain, WQ, WK, QD, KD);
    csr_aggw<<<(N_TOTAL + 3) / 4, 256, 0, stream>>>(OFF, META, QD, KD, Ain, AGG);
    // transform: Hf = elu(AGG[30000,768] @ Wstack[768,128] + b + SL), fused.
    // BM=32 (MI=1): 938 blocks vs 469 — fixes the 1.8-blocks/CU TLP
    // starvation; B re-reads (192 KB) are L2-resident; same sum order.
    GB g;
    g.A[0] = AGG; g.Bt[0] = Wstk; g.bias[0] = bb; g.add[0] = SL; g.C[0] = Hf;
    g.K[0] = NREL * 128; g.Kp[0] = NREL * 128;
    gemm_mfma<1, true, true, true><<<dim3(gridM_t32, 1, 1), 256, 0, stream>>>(g, N_TOTAL);
  }

  // ---- head (BM=64) ----
  {
    GB g;
    g.A[0] = Hf; g.Bt[0] = cw.dst[8]; g.bias[0] = lin1b; g.add[0] = nullptr; g.C[0] = Z;
    g.K[0] = 128; g.Kp[0] = 128;
    gemm_mfma<2, true, true, false><<<dim3(gridM_per, 1, 1), 256, 0, stream>>>(g, NPER);
  }
  lin2_kernel<<<(NPER + 3) / 4, 256, 0, stream>>>(Z, lin2W, lin2b, (float*)d_out);
}